// Round 4
// baseline (499.565 us; speedup 1.0000x reference)
//
#include <hip/hip_runtime.h>
#include <hip/hip_bf16.h>
#include <math.h>

// ---------------------------------------------------------------------------
// TransformerBlock: B=8 T=1024 C=1024 H=16 d=64, bf16 MFMA compute, fp32 acc.
// R9: all GEMMs -> m97-structure 128x128 kernel (256 thr / 4 waves, single-
//     buffered 32KB LDS 2-barrier K-loop, 36KB total -> 4 blocks/CU for
//     wave-level overlap across blocks, the m114 mechanism). Zero-conflict
//     swizzle staging + coalesced LDS-restage epilogues carried over.
//     Attn/LN/transposes unchanged.
// ---------------------------------------------------------------------------

#define DEVI __device__ __forceinline__

typedef __attribute__((ext_vector_type(4))) float floatx4;
typedef __attribute__((ext_vector_type(8))) short shortx8;   // 8 bf16 = 4 VGPRs

DEVI ushort f2b(float f) {
    __hip_bfloat16 h = __float2bfloat16(f);
    return __builtin_bit_cast(ushort, h);
}

DEVI void gl_lds16(const ushort* g, ushort* l) {
    // 16B direct global->LDS. LDS dest = wave-uniform base + lane*16.
    __builtin_amdgcn_global_load_lds(
        (const __attribute__((address_space(1))) void*)g,
        (__attribute__((address_space(3))) void*)l, 16, 0, 0);
}

// tanh-form GeLU: |err| vs erf-GeLU ~3e-3 — far under the bf16 threshold.
DEVI float gelu_f(float v) {
    const float u0 = 0.7978845608f * v * (1.0f + 0.044715f * v * v);
    const float u  = fminf(fmaxf(u0, -15.0f), 15.0f);
    const float e  = exp2f(u * 2.885390082f);      // e^{2u}
    const float th = 1.0f - 2.0f / (e + 1.0f);     // tanh(u)
    return 0.5f * v * (1.0f + th);
}

// ---------------------------------------------------------------------------
// Fused transpose of the four 1024x1024 weights (z picks the matrix).
// ---------------------------------------------------------------------------
__global__ void transp4_kernel(const float* __restrict__ s0, const float* __restrict__ s1,
                               const float* __restrict__ s2, const float* __restrict__ s3,
                               ushort* __restrict__ d0, ushort* __restrict__ d1,
                               ushort* __restrict__ d2, ushort* __restrict__ d3) {
    const int z = blockIdx.z;
    const float* src = (z == 0) ? s0 : (z == 1) ? s1 : (z == 2) ? s2 : s3;
    ushort*      dst = (z == 0) ? d0 : (z == 1) ? d1 : (z == 2) ? d2 : d3;
    __shared__ float tile[32][33];
    const int c0 = blockIdx.x * 32, r0 = blockIdx.y * 32;
    const int tx = threadIdx.x, ty = threadIdx.y;   // 32 x 8
#pragma unroll
    for (int i = 0; i < 32; i += 8)
        tile[ty + i][tx] = src[(size_t)(r0 + ty + i) * 1024 + c0 + tx];
    __syncthreads();
#pragma unroll
    for (int i = 0; i < 32; i += 8)
        dst[(size_t)(c0 + ty + i) * 1024 + r0 + tx] = f2b(tile[tx][ty + i]);
}

__global__ void transp_kernel(const float* __restrict__ src,
                              ushort* __restrict__ dst, int R, int C) {
    __shared__ float tile[32][33];
    const int c0 = blockIdx.x * 32, r0 = blockIdx.y * 32;
    const int tx = threadIdx.x, ty = threadIdx.y;   // 32 x 8
#pragma unroll
    for (int i = 0; i < 32; i += 8)
        tile[ty + i][tx] = src[(size_t)(r0 + ty + i) * C + c0 + tx];
    __syncthreads();
#pragma unroll
    for (int i = 0; i < 32; i += 8)
        dst[(size_t)(c0 + ty + i) * R + r0 + tx] = f2b(tile[tx][ty + i]);
}

// ---------------------------------------------------------------------------
// LayerNorm over C=1024, one block (256 thr) per token. fp32 in, bf16 out.
// ---------------------------------------------------------------------------
__global__ __launch_bounds__(256)
void ln_kernel(const float* __restrict__ x, const float* __restrict__ w,
               const float* __restrict__ b, ushort* __restrict__ out) {
    __shared__ float red[8];
    const int m = blockIdx.x;
    const int tid = threadIdx.x;
    const float4 xv = *(const float4*)&x[(size_t)m * 1024 + tid * 4];
    float s  = xv.x + xv.y + xv.z + xv.w;
    float s2 = xv.x * xv.x + xv.y * xv.y + xv.z * xv.z + xv.w * xv.w;
#pragma unroll
    for (int o = 32; o >= 1; o >>= 1) {
        s  += __shfl_xor(s, o, 64);
        s2 += __shfl_xor(s2, o, 64);
    }
    const int wv_ = tid >> 6;
    if ((tid & 63) == 0) { red[wv_] = s; red[4 + wv_] = s2; }
    __syncthreads();
    s  = red[0] + red[1] + red[2] + red[3];
    s2 = red[4] + red[5] + red[6] + red[7];
    const float mu   = s * (1.0f / 1024.0f);
    const float var  = s2 * (1.0f / 1024.0f) - mu * mu;
    const float rstd = rsqrtf(var + 1e-5f);
    const float4 wv = *(const float4*)&w[tid * 4];
    const float4 bv = *(const float4*)&b[tid * 4];
    ushort o4[4];
    o4[0] = f2b((xv.x - mu) * rstd * wv.x + bv.x);
    o4[1] = f2b((xv.y - mu) * rstd * wv.y + bv.y);
    o4[2] = f2b((xv.z - mu) * rstd * wv.z + bv.z);
    o4[3] = f2b((xv.w - mu) * rstd * wv.w + bv.w);
    *(uint2*)&out[(size_t)m * 1024 + tid * 4] = *(uint2*)o4;
}

// ---------------------------------------------------------------------------
// gemm97: 128x128 tile, 256 thr = 4 waves (2x2), wave-tile 64x64 as 4x4 of
// mfma_f32_16x16x32_bf16. Single-buffered 32KB LDS (A 16K | B 16K), 2-barrier
// K-loop with global_load_lds staging; compiler schedules ds_read/MFMA with
// fine lgkmcnt (m97 structure, 874-912 TF measured; wins come from 4 blocks/CU
// overlapping each other's barrier drains — m114).
//   MODE 1: fused QKV epilogue (Q/K head layout; V^T via LDS transpose)
//   MODE 2: fp32 out = acc + bias + resid (coalesced via LDS restage)
//   MODE 3: bf16 out = gelu(acc + bias)
// LDS swizzle (verified, 0 conflicts): LDS[r][c] = src[r][c ^ (r&7)] (8-ushort
// chunks); fragment read chunk = (lane>>4) ^ (lane&7), ks flips ^32 ushorts.
// ---------------------------------------------------------------------------
template <int MODE>
__global__ __launch_bounds__(256, 4)
void gemm97(const ushort* __restrict__ A, const ushort* __restrict__ Bt,
            const float* __restrict__ biasQ, const float* __restrict__ biasK,
            const float* __restrict__ biasV,
            void* __restrict__ out, void* __restrict__ out2, void* __restrict__ out3,
            const float* __restrict__ resid, int N, int K) {
    __shared__ __align__(128) ushort lds[18432];   // 36 KB (32K staging + epi slack)

    const int tid  = threadIdx.x;
    const int lane = tid & 63;
    const int w    = tid >> 6;       // 0..3
    const int wr   = w >> 1;         // 0..1 (M half)
    const int wc   = w & 1;          // 0..1 (N half)

    // XCD-aware bijective block swizzle (nwg % 8 == 0 for all our grids)
    int bx = blockIdx.x, by = blockIdx.y;
    {
        const int nwg = gridDim.x * gridDim.y;
        if ((nwg & 7) == 0) {
            const int flat = by * gridDim.x + bx;
            const int cpx  = nwg >> 3;
            const int wg   = (flat & 7) * cpx + (flat >> 3);
            bx = wg % gridDim.x;
            by = wg / gridDim.x;
        }
    }
    const int m0 = by * 128;
    const int n0 = bx * 128;

    floatx4 acc[4][4] = {};          // [mi][ni] 16x16 frags

    // ---- staging (global source pre-swizzled, LDS dest linear) ----
    const int lr3 = lane >> 3;             // 0..7
    const int sc  = (lane & 7) ^ lr3;      // swizzled source col-chunk
    const ushort* pA = A  + (size_t)(m0 + w * 32 + lr3) * K + sc * 8;
    const ushort* pB = Bt + (size_t)(n0 + w * 32 + lr3) * K + sc * 8;
    ushort* sAd = lds + w * 2048;
    ushort* sBd = lds + 8192 + w * 2048;
    const size_t k8 = (size_t)8 * K, k16 = (size_t)16 * K, k24 = (size_t)24 * K;

    // ---- fragment read pointers (swizzled on read) ----
    const int c0f = (lane >> 4) ^ (lane & 7);
    const int aIdx = (wr * 64 + (lane & 15)) * 64 + c0f * 8;
    const int bIdx = (wc * 64 + (lane & 15)) * 64 + c0f * 8;
    const ushort* ar0 = lds + aIdx;
    const ushort* ar1 = lds + (aIdx ^ 32);          // ks=1: source k-chunk +4
    const ushort* br0 = lds + 8192 + bIdx;
    const ushort* br1 = lds + 8192 + (bIdx ^ 32);

    for (int k0 = 0; k0 < K; k0 += 64) {
        __syncthreads();                 // prev tile's reads complete
        gl_lds16(pA + k0,       sAd);
        gl_lds16(pA + k8  + k0, sAd + 512);
        gl_lds16(pA + k16 + k0, sAd + 1024);
        gl_lds16(pA + k24 + k0, sAd + 1536);
        gl_lds16(pB + k0,       sBd);
        gl_lds16(pB + k8  + k0, sBd + 512);
        gl_lds16(pB + k16 + k0, sBd + 1024);
        gl_lds16(pB + k24 + k0, sBd + 1536);
        asm volatile("s_waitcnt vmcnt(0)" ::: "memory");
        __syncthreads();                 // tile staged

        shortx8 af[4][2], bf[4][2];
#pragma unroll
        for (int mi = 0; mi < 4; ++mi) {
            af[mi][0] = *(const shortx8*)&ar0[mi * 1024];
            af[mi][1] = *(const shortx8*)&ar1[mi * 1024];
        }
#pragma unroll
        for (int ni = 0; ni < 4; ++ni) {
            bf[ni][0] = *(const shortx8*)&br0[ni * 1024];
            bf[ni][1] = *(const shortx8*)&br1[ni * 1024];
        }
#pragma unroll
        for (int mi = 0; mi < 4; ++mi)
#pragma unroll
            for (int ni = 0; ni < 4; ++ni) {
                acc[mi][ni] = __builtin_amdgcn_mfma_f32_16x16x32_bf16(
                    af[mi][0], bf[ni][0], acc[mi][ni], 0, 0, 0);
                acc[mi][ni] = __builtin_amdgcn_mfma_f32_16x16x32_bf16(
                    af[mi][1], bf[ni][1], acc[mi][ni], 0, 0, 0);
            }
    }
    __syncthreads();                     // loop reads done; lds reusable

    // ---- epilogue. C/D map (16x16x32): row=(lane>>4)*4+reg, col=lane&15.
    const int colL  = wc * 64 + (lane & 15);          // + ni*16
    const int rbase = wr * 64 + ((lane >> 4) << 2);   // + mi*16 + r

    if constexpr (MODE == 3) {           // bf16 gelu(acc+bias), row-major out
        float bvals[4];
#pragma unroll
        for (int ni = 0; ni < 4; ++ni) bvals[ni] = biasQ[n0 + colL + ni * 16];
        ushort* T = lds;                 // [128][136]
#pragma unroll
        for (int mi = 0; mi < 4; ++mi)
#pragma unroll
        for (int ni = 0; ni < 4; ++ni) {
            const int t0 = rbase + mi * 16;
#pragma unroll
            for (int r = 0; r < 4; ++r)
                T[(t0 + r) * 136 + colL + ni * 16] =
                    f2b(gelu_f(acc[mi][ni][r] + bvals[ni]));
        }
        __syncthreads();
        ushort* o = (ushort*)out;
#pragma unroll
        for (int it = 0; it < 8; ++it) {
            const int idx = it * 256 + tid;
            const int row = idx >> 4, ch = idx & 15;
            const uint4 vv = *(const uint4*)&T[row * 136 + ch * 8];
            *(uint4*)&o[(size_t)(m0 + row) * N + n0 + ch * 8] = vv;
        }
    }

    if constexpr (MODE == 2) {           // fp32 acc + bias + resid
        float bvals[4];
#pragma unroll
        for (int ni = 0; ni < 4; ++ni) bvals[ni] = biasQ[n0 + colL + ni * 16];
        float* T = (float*)lds;          // [64][132] per half
        float* o = (float*)out;
#pragma unroll
        for (int half = 0; half < 2; ++half) {
            if (wr == half) {
#pragma unroll
                for (int mi = 0; mi < 4; ++mi)
#pragma unroll
                for (int ni = 0; ni < 4; ++ni) {
                    const int t0 = mi * 16 + ((lane >> 4) << 2);
#pragma unroll
                    for (int r = 0; r < 4; ++r)
                        T[(t0 + r) * 132 + colL + ni * 16] =
                            acc[mi][ni][r] + bvals[ni];
                }
            }
            __syncthreads();
#pragma unroll
            for (int it = 0; it < 8; ++it) {
                const int idx = it * 256 + tid;
                const int row = idx >> 5, ch = idx & 31;
                float4 tv = *(const float4*)&T[row * 132 + ch * 4];
                const size_t go = (size_t)(m0 + half * 64 + row) * N + n0 + ch * 4;
                const float4 rv = *(const float4*)&resid[go];
                tv.x += rv.x; tv.y += rv.y; tv.z += rv.z; tv.w += rv.w;
                *(float4*)&o[go] = tv;
            }
            __syncthreads();
        }
    }

    if constexpr (MODE == 1) {           // fused QKV
        const int mat   = n0 >> 10;      // 0=Q, 1=K, 2=V (block-uniform)
        const int bb    = m0 >> 10;
        const int tbase = m0 & 1023;
        if (mat < 2) {
            const float* bp = (mat == 0) ? biasQ : biasK;
            ushort* dst = (mat == 0) ? (ushort*)out : (ushort*)out2;
            float bvals[4];
#pragma unroll
            for (int ni = 0; ni < 4; ++ni)
                bvals[ni] = bp[(n0 & 1023) + colL + ni * 16];
            ushort* T = lds;             // [128][136]
#pragma unroll
            for (int mi = 0; mi < 4; ++mi)
#pragma unroll
            for (int ni = 0; ni < 4; ++ni) {
                const int t0 = rbase + mi * 16;
#pragma unroll
                for (int r = 0; r < 4; ++r)
                    T[(t0 + r) * 136 + colL + ni * 16] =
                        f2b(acc[mi][ni][r] + bvals[ni]);
            }
            __syncthreads();
#pragma unroll
            for (int it = 0; it < 8; ++it) {
                const int idx = it * 256 + tid;
                const int row = idx >> 4, ch = idx & 15;
                const uint4 vv = *(const uint4*)&T[row * 136 + ch * 8];
                const int cg = (n0 & 1023) + ch * 8;   // 8 cols, single head
                const int h = cg >> 6, dd = cg & 63;
                const int t = tbase + row;
                *(uint4*)&dst[((size_t)(bb * 16 + h) * 1024 + t) * 64 + dd] = vv;
            }
        } else {
            // V: transpose 128(t) x 128(dim) through LDS -> Vt [b,h][d][t]
            const int vb = n0 - 2048;
            ushort* T = lds;             // [128 dim][136 t-pad]
            ushort* Vt = (ushort*)out3;
#pragma unroll
            for (int ni = 0; ni < 4; ++ni) {
                const float bv = biasV[vb + colL + ni * 16];
#pragma unroll
                for (int mi = 0; mi < 4; ++mi) {
                    const int t0 = rbase + mi * 16;
#pragma unroll
                    for (int r = 0; r < 4; ++r)
                        T[(colL + ni * 16) * 136 + t0 + r] =
                            f2b(acc[mi][ni][r] + bv);
                }
            }
            __syncthreads();
#pragma unroll
            for (int it = 0; it < 8; ++it) {
                const int idx = it * 256 + tid;
                const int dim = idx >> 4, ch = idx & 15;
                const uint4 vv = *(const uint4*)&T[dim * 136 + ch * 8];
                const int d  = vb + dim;
                const int hh = d >> 6, dl = d & 63;
                *(uint4*)&Vt[((size_t)(bb * 16 + hh) * 64 + dl) * 1024 + tbase + ch * 8] = vv;
            }
        }
    }
}

// ---------------------------------------------------------------------------
// Flash-style causal attention, LDS-staged (unchanged).
// ---------------------------------------------------------------------------
__global__ __launch_bounds__(256)
void attn_kernel(const ushort* __restrict__ Q, const ushort* __restrict__ Kk,
                 const ushort* __restrict__ Vt, ushort* __restrict__ ctx) {
    __shared__ ushort sK[64 * 64];
    __shared__ ushort sV[64 * 64];     // V^T tile: [d][64 kv-cols]
    __shared__ ushort sP[4][16 * 72];

    const int tid  = threadIdx.x;
    const int lane = tid & 63;
    const int wave = tid >> 6;
    const int quad = lane >> 4;
    const int l15  = lane & 15;

    const int qb = 15 - (blockIdx.x >> 7);   // descending workload
    const int bh = blockIdx.x & 127;
    const size_t base = (size_t)bh << 16;    // bh*1024*64
    const int bb = bh >> 4, h = bh & 15;

    const int lrow = lane >> 3;
    const int scb  = (lane & 7) ^ lrow;
    const ushort* Kg = Kk + base + (size_t)(wave * 8 + lrow) * 64 + scb * 8;
    const ushort* Vg = Vt + base + (size_t)(wave * 8 + lrow) * 1024 + scb * 8;

    const int qrow = qb * 64 + wave * 16 + l15;
    const shortx8 qf0 = *(const shortx8*)&Q[base + (size_t)qrow * 64 + quad * 8];
    const shortx8 qf1 = *(const shortx8*)&Q[base + (size_t)qrow * 64 + 32 + quad * 8];

    const float SC = 0.125f * 1.44269504f;   // exp2-domain scaling

    float mstate[4], lstate[4];
    floatx4 oacc[4] = {};
#pragma unroll
    for (int r = 0; r < 4; ++r) { mstate[r] = -__builtin_inff(); lstate[r] = 0.0f; }

    for (int kt = 0; kt <= qb; ++kt) {
        __syncthreads();
#pragma unroll
        for (int p = 0; p < 2; ++p) {
            gl_lds16(Kg + (size_t)kt * 4096 + (size_t)p * 2048,
                     sK + (p * 32 + wave * 8) * 64);
            gl_lds16(Vg + (size_t)kt * 64 + (size_t)p * 32 * 1024,
                     sV + (p * 32 + wave * 8) * 64);
        }
        __syncthreads();

        floatx4 s[4];
#pragma unroll
        for (int nt = 0; nt < 4; ++nt) {
            const int r = nt * 16 + l15;
            const int c0 = quad ^ (r & 7);
            const int c1 = (4 + quad) ^ (r & 7);
            const shortx8 kf0 = *(const shortx8*)&sK[r * 64 + c0 * 8];
            const shortx8 kf1 = *(const shortx8*)&sK[r * 64 + c1 * 8];
            floatx4 z = {};
            z = __builtin_amdgcn_mfma_f32_16x16x32_bf16(qf0, kf0, z, 0, 0, 0);
            z = __builtin_amdgcn_mfma_f32_16x16x32_bf16(qf1, kf1, z, 0, 0, 0);
            s[nt] = z;
        }
#pragma unroll
        for (int nt = 0; nt < 4; ++nt)
#pragma unroll
            for (int r = 0; r < 4; ++r) {
                float sv = s[nt][r] * SC;
                if (kt == qb) {
                    const int col = nt * 16 + l15;
                    const int row = wave * 16 + quad * 4 + r;
                    if (col > row) sv = -__builtin_inff();
                }
                s[nt][r] = sv;
            }
        float mnew[4], alpha[4];
#pragma unroll
        for (int r = 0; r < 4; ++r) {
            float mt = fmaxf(fmaxf(s[0][r], s[1][r]), fmaxf(s[2][r], s[3][r]));
#pragma unroll
            for (int o = 8; o >= 1; o >>= 1) mt = fmaxf(mt, __shfl_xor(mt, o, 64));
            mnew[r]  = fmaxf(mstate[r], mt);
            alpha[r] = exp2f(mstate[r] - mnew[r]);
            mstate[r] = mnew[r];
        }
#pragma unroll
        for (int r = 0; r < 4; ++r) {
            float rs = 0.0f;
#pragma unroll
            for (int nt = 0; nt < 4; ++nt) {
                const float p = exp2f(s[nt][r] - mnew[r]);
                s[nt][r] = p;
                rs += p;
            }
#pragma unroll
            for (int o = 8; o >= 1; o >>= 1) rs += __shfl_xor(rs, o, 64);
            lstate[r] = alpha[r] * lstate[r] + rs;
#pragma unroll
            for (int dt = 0; dt < 4; ++dt) oacc[dt][r] *= alpha[r];
        }
#pragma unroll
        for (int nt = 0; nt < 4; ++nt)
#pragma unroll
            for (int r = 0; r < 4; ++r)
                sP[wave][(quad * 4 + r) * 72 + nt * 16 + l15] = f2b(s[nt][r]);
        __asm__ volatile("s_waitcnt lgkmcnt(0)" ::: "memory");
        const shortx8 pf0 = *(const shortx8*)&sP[wave][l15 * 72 + quad * 8];
        const shortx8 pf1 = *(const shortx8*)&sP[wave][l15 * 72 + 32 + quad * 8];
#pragma unroll
        for (int dt = 0; dt < 4; ++dt) {
            const int r = dt * 16 + l15;
            const int c0 = quad ^ (r & 7);
            const int c1 = (4 + quad) ^ (r & 7);
            const shortx8 v0 = *(const shortx8*)&sV[r * 64 + c0 * 8];
            const shortx8 v1 = *(const shortx8*)&sV[r * 64 + c1 * 8];
            oacc[dt] = __builtin_amdgcn_mfma_f32_16x16x32_bf16(pf0, v0, oacc[dt], 0, 0, 0);
            oacc[dt] = __builtin_amdgcn_mfma_f32_16x16x32_bf16(pf1, v1, oacc[dt], 0, 0, 0);
        }
    }
#pragma unroll
    for (int dt = 0; dt < 4; ++dt)
#pragma unroll
        for (int r = 0; r < 4; ++r) {
            const int t = qb * 64 + wave * 16 + quad * 4 + r;
            const int dim = dt * 16 + l15;
            const float v = oacc[dt][r] / lstate[r];
            ctx[(size_t)(bb * 1024 + t) * 1024 + h * 64 + dim] = f2b(v);
        }
}

// ---------------------------------------------------------------------------
// Launch
// ---------------------------------------------------------------------------
extern "C" void kernel_launch(void* const* d_in, const int* in_sizes, int n_in,
                              void* d_out, int out_size, void* d_ws, size_t ws_size,
                              hipStream_t stream) {
    const float* x    = (const float*)d_in[0];
    const float* ln1w = (const float*)d_in[2];
    const float* ln1b = (const float*)d_in[3];
    const float* ln2w = (const float*)d_in[4];
    const float* ln2b = (const float*)d_in[5];
    const float* wq   = (const float*)d_in[6];
    const float* bq   = (const float*)d_in[7];
    const float* wk   = (const float*)d_in[8];
    const float* bk   = (const float*)d_in[9];
    const float* wv   = (const float*)d_in[10];
    const float* bv   = (const float*)d_in[11];
    const float* wo   = (const float*)d_in[12];
    const float* bo   = (const float*)d_in[13];
    const float* w1   = (const float*)d_in[14];
    const float* b1   = (const float*)d_in[15];
    const float* w2   = (const float*)d_in[16];
    const float* b2   = (const float*)d_in[17];

    char* ws = (char*)d_ws;
    const size_t MB = 1024 * 1024;
    ushort* WQKVT = (ushort*)(ws + 0 * MB);     // [3072][1024] bf16 (wq|wk|wv ^T)
    ushort* WOT   = (ushort*)(ws + 6 * MB);     // [1024][1024]
    ushort* W1T   = (ushort*)(ws + 8 * MB);     // [4096][1024]
    ushort* W2T   = (ushort*)(ws + 16 * MB);    // [1024][4096]
    ushort* H1    = (ushort*)(ws + 24 * MB);    // [8192][1024]; H2 overlays later
    ushort* H2    = H1;
    ushort* Qb    = (ushort*)(ws + 40 * MB);    // [128][1024][64]
    ushort* Kb    = (ushort*)(ws + 56 * MB);    // [128][1024][64]
    ushort* Vbt   = (ushort*)(ws + 72 * MB);    // [128][64][1024]
    ushort* FF1   = (ushort*)(ws + 40 * MB);    // [8192][4096] overlays Q,K,V (dead)
    ushort* CTX   = (ushort*)(ws + 104 * MB);   // [8192][1024]

    float* xout = (float*)d_out;                // x2 lives here, then final out

    const dim3 tb(32, 8);
    transp4_kernel<<<dim3(32, 32, 4), tb, 0, stream>>>(
        wq, wk, wv, wo,
        WQKVT, WQKVT + 1024 * 1024, WQKVT + 2048 * 1024, WOT);
    transp_kernel<<<dim3(128, 32), tb, 0, stream>>>(w1, W1T, 1024, 4096);
    transp_kernel<<<dim3(32, 128), tb, 0, stream>>>(w2, W2T, 4096, 1024);

    ln_kernel<<<8192, 256, 0, stream>>>(x, ln1w, ln1b, H1);

    gemm97<1><<<dim3(24, 64), 256, 0, stream>>>(H1, WQKVT, bq, bk, bv,
                                                Qb, Kb, Vbt, nullptr, 3072, 1024);

    attn_kernel<<<2048, 256, 0, stream>>>(Qb, Kb, Vbt, CTX);

    gemm97<2><<<dim3(8, 64), 256, 0, stream>>>(CTX, WOT, bo, nullptr, nullptr,
                                               xout, nullptr, nullptr, x, 1024, 1024);

    ln_kernel<<<8192, 256, 0, stream>>>(xout, ln2w, ln2b, H2);

    gemm97<3><<<dim3(32, 64), 256, 0, stream>>>(H2, W1T, b1, nullptr, nullptr,
                                                FF1, nullptr, nullptr, nullptr, 4096, 1024);

    gemm97<2><<<dim3(8, 64), 256, 0, stream>>>(FF1, W2T, b2, nullptr, nullptr,
                                               xout, nullptr, nullptr, xout, 1024, 4096);

    (void)in_sizes; (void)n_in; (void)out_size; (void)ws_size;
}

// Round 5
// 468.217 us; speedup vs baseline: 1.0670x; 1.0670x over previous
//
#include <hip/hip_runtime.h>
#include <hip/hip_bf16.h>
#include <math.h>

// ---------------------------------------------------------------------------
// TransformerBlock: B=8 T=1024 C=1024 H=16 d=64, bf16 MFMA compute, fp32 acc.
// R10: QKV + FFN1 -> gemmW: 256x128 tile, 8 waves, 48KB single-buffered LDS,
//      m97 2-barrier K-loop (bytes/FLOP -25% vs 128^2; 2 blocks/CU).
//      Q,K now emitted TOKEN-MAJOR [8192][1024] (coalesced row-major stores;
//      kills the 128B partial-line head-scatter). V stays [b,h][d][t].
//      attn re-indexes Q/K reads accordingly. Wo/FFN2 keep gemm97<2> (R9).
// ---------------------------------------------------------------------------

#define DEVI __device__ __forceinline__

typedef __attribute__((ext_vector_type(4))) float floatx4;
typedef __attribute__((ext_vector_type(8))) short shortx8;   // 8 bf16 = 4 VGPRs

DEVI ushort f2b(float f) {
    __hip_bfloat16 h = __float2bfloat16(f);
    return __builtin_bit_cast(ushort, h);
}

DEVI void gl_lds16(const ushort* g, ushort* l) {
    // 16B direct global->LDS. LDS dest = wave-uniform base + lane*16.
    __builtin_amdgcn_global_load_lds(
        (const __attribute__((address_space(1))) void*)g,
        (__attribute__((address_space(3))) void*)l, 16, 0, 0);
}

// tanh-form GeLU: |err| vs erf-GeLU ~3e-3 — far under the bf16 threshold.
DEVI float gelu_f(float v) {
    const float u0 = 0.7978845608f * v * (1.0f + 0.044715f * v * v);
    const float u  = fminf(fmaxf(u0, -15.0f), 15.0f);
    const float e  = exp2f(u * 2.885390082f);      // e^{2u}
    const float th = 1.0f - 2.0f / (e + 1.0f);     // tanh(u)
    return 0.5f * v * (1.0f + th);
}

// ---------------------------------------------------------------------------
// Fused transpose of the four 1024x1024 weights (z picks the matrix).
// ---------------------------------------------------------------------------
__global__ void transp4_kernel(const float* __restrict__ s0, const float* __restrict__ s1,
                               const float* __restrict__ s2, const float* __restrict__ s3,
                               ushort* __restrict__ d0, ushort* __restrict__ d1,
                               ushort* __restrict__ d2, ushort* __restrict__ d3) {
    const int z = blockIdx.z;
    const float* src = (z == 0) ? s0 : (z == 1) ? s1 : (z == 2) ? s2 : s3;
    ushort*      dst = (z == 0) ? d0 : (z == 1) ? d1 : (z == 2) ? d2 : d3;
    __shared__ float tile[32][33];
    const int c0 = blockIdx.x * 32, r0 = blockIdx.y * 32;
    const int tx = threadIdx.x, ty = threadIdx.y;   // 32 x 8
#pragma unroll
    for (int i = 0; i < 32; i += 8)
        tile[ty + i][tx] = src[(size_t)(r0 + ty + i) * 1024 + c0 + tx];
    __syncthreads();
#pragma unroll
    for (int i = 0; i < 32; i += 8)
        dst[(size_t)(c0 + ty + i) * 1024 + r0 + tx] = f2b(tile[tx][ty + i]);
}

__global__ void transp_kernel(const float* __restrict__ src,
                              ushort* __restrict__ dst, int R, int C) {
    __shared__ float tile[32][33];
    const int c0 = blockIdx.x * 32, r0 = blockIdx.y * 32;
    const int tx = threadIdx.x, ty = threadIdx.y;   // 32 x 8
#pragma unroll
    for (int i = 0; i < 32; i += 8)
        tile[ty + i][tx] = src[(size_t)(r0 + ty + i) * C + c0 + tx];
    __syncthreads();
#pragma unroll
    for (int i = 0; i < 32; i += 8)
        dst[(size_t)(c0 + ty + i) * R + r0 + tx] = f2b(tile[tx][ty + i]);
}

// ---------------------------------------------------------------------------
// LayerNorm over C=1024, one block (256 thr) per token. fp32 in, bf16 out.
// ---------------------------------------------------------------------------
__global__ __launch_bounds__(256)
void ln_kernel(const float* __restrict__ x, const float* __restrict__ w,
               const float* __restrict__ b, ushort* __restrict__ out) {
    __shared__ float red[8];
    const int m = blockIdx.x;
    const int tid = threadIdx.x;
    const float4 xv = *(const float4*)&x[(size_t)m * 1024 + tid * 4];
    float s  = xv.x + xv.y + xv.z + xv.w;
    float s2 = xv.x * xv.x + xv.y * xv.y + xv.z * xv.z + xv.w * xv.w;
#pragma unroll
    for (int o = 32; o >= 1; o >>= 1) {
        s  += __shfl_xor(s, o, 64);
        s2 += __shfl_xor(s2, o, 64);
    }
    const int wv_ = tid >> 6;
    if ((tid & 63) == 0) { red[wv_] = s; red[4 + wv_] = s2; }
    __syncthreads();
    s  = red[0] + red[1] + red[2] + red[3];
    s2 = red[4] + red[5] + red[6] + red[7];
    const float mu   = s * (1.0f / 1024.0f);
    const float var  = s2 * (1.0f / 1024.0f) - mu * mu;
    const float rstd = rsqrtf(var + 1e-5f);
    const float4 wv = *(const float4*)&w[tid * 4];
    const float4 bv = *(const float4*)&b[tid * 4];
    ushort o4[4];
    o4[0] = f2b((xv.x - mu) * rstd * wv.x + bv.x);
    o4[1] = f2b((xv.y - mu) * rstd * wv.y + bv.y);
    o4[2] = f2b((xv.z - mu) * rstd * wv.z + bv.z);
    o4[3] = f2b((xv.w - mu) * rstd * wv.w + bv.w);
    *(uint2*)&out[(size_t)m * 1024 + tid * 4] = *(uint2*)o4;
}

// ---------------------------------------------------------------------------
// gemmW: 256(M) x 128(N) tile, 512 thr = 8 waves (4M x 2N), wave-tile 64x64
// as 4x4 of mfma_f32_16x16x32_bf16. Single-buffered 48KB LDS (A 32K | B 16K),
// m97 2-barrier K-loop, global_load_lds staging, verified zero-conflict
// swizzle: LDS[r][c] = src[r][c ^ (r&7)]; read chunk (lane>>4)^(lane&7).
//   MODE 1: Q/K token-major row store; V -> [b,h][d][t] via LDS transpose
//   MODE 3: bf16 out = gelu(acc + bias), row-major
// ---------------------------------------------------------------------------
template <int MODE>
__global__ __launch_bounds__(512, 4)
void gemmW(const ushort* __restrict__ A, const ushort* __restrict__ Bt,
           const float* __restrict__ biasQ, const float* __restrict__ biasK,
           const float* __restrict__ biasV,
           void* __restrict__ out, void* __restrict__ out2, void* __restrict__ out3,
           int N, int K) {
    __shared__ __align__(128) ushort lds[24576];   // 48 KB: sA 256x64 | sB 128x64

    const int tid  = threadIdx.x;
    const int lane = tid & 63;
    const int w    = tid >> 6;       // 0..7
    const int wr   = w >> 1;         // 0..3 (64-row band)
    const int wc   = w & 1;          // 0..1 (64-col half)

    // XCD-aware bijective block swizzle (nwg % 8 == 0 for all our grids)
    int bx = blockIdx.x, by = blockIdx.y;
    {
        const int nwg = gridDim.x * gridDim.y;
        if ((nwg & 7) == 0) {
            const int flat = by * gridDim.x + bx;
            const int cpx  = nwg >> 3;
            const int wg   = (flat & 7) * cpx + (flat >> 3);
            bx = wg % gridDim.x;
            by = wg / gridDim.x;
        }
    }
    const int m0 = by * 256;
    const int n0 = bx * 128;

    floatx4 acc[4][4] = {};          // [mi][ni] 16x16 frags (wave 64x64)

    // ---- staging (global source pre-swizzled, LDS dest linear) ----
    const int lr3 = lane >> 3;             // 0..7
    const int sc  = (lane & 7) ^ lr3;      // swizzled source col-chunk
    const ushort* pA = A  + (size_t)(m0 + w * 32 + lr3) * K + sc * 8;
    const ushort* pB = Bt + (size_t)(n0 + w * 16 + lr3) * K + sc * 8;
    ushort* sAd = lds + w * 2048;                   // 32 rows x 64
    ushort* sBd = lds + 16384 + w * 1024;           // 16 rows x 64
    const size_t k8 = (size_t)8 * K, k16 = (size_t)16 * K, k24 = (size_t)24 * K;

    // ---- fragment read pointers (swizzled on read) ----
    const int c0f  = (lane >> 4) ^ (lane & 7);
    const int aIdx = (wr * 64 + (lane & 15)) * 64 + c0f * 8;
    const int bIdx = (wc * 64 + (lane & 15)) * 64 + c0f * 8;
    const ushort* ar0 = lds + aIdx;
    const ushort* ar1 = lds + (aIdx ^ 32);          // ks=1: k-chunk +4
    const ushort* br0 = lds + 16384 + bIdx;
    const ushort* br1 = lds + 16384 + (bIdx ^ 32);

    for (int k0 = 0; k0 < K; k0 += 64) {
        __syncthreads();                 // prev tile's reads complete
        gl_lds16(pA + k0,       sAd);
        gl_lds16(pA + k8  + k0, sAd + 512);
        gl_lds16(pA + k16 + k0, sAd + 1024);
        gl_lds16(pA + k24 + k0, sAd + 1536);
        gl_lds16(pB + k0,       sBd);
        gl_lds16(pB + k8  + k0, sBd + 512);
        asm volatile("s_waitcnt vmcnt(0)" ::: "memory");
        __syncthreads();                 // tile staged

        shortx8 af[4][2], bf[4][2];
#pragma unroll
        for (int mi = 0; mi < 4; ++mi) {
            af[mi][0] = *(const shortx8*)&ar0[mi * 1024];
            af[mi][1] = *(const shortx8*)&ar1[mi * 1024];
        }
#pragma unroll
        for (int ni = 0; ni < 4; ++ni) {
            bf[ni][0] = *(const shortx8*)&br0[ni * 1024];
            bf[ni][1] = *(const shortx8*)&br1[ni * 1024];
        }
#pragma unroll
        for (int mi = 0; mi < 4; ++mi)
#pragma unroll
            for (int ni = 0; ni < 4; ++ni) {
                acc[mi][ni] = __builtin_amdgcn_mfma_f32_16x16x32_bf16(
                    af[mi][0], bf[ni][0], acc[mi][ni], 0, 0, 0);
                acc[mi][ni] = __builtin_amdgcn_mfma_f32_16x16x32_bf16(
                    af[mi][1], bf[ni][1], acc[mi][ni], 0, 0, 0);
            }
    }
    __syncthreads();                     // loop reads done; lds reusable

    // ---- epilogue. C/D map (16x16x32): row=(lane>>4)*4+reg, col=lane&15.
    // Wave rows: wr*64 + mi*16 + (lane>>4)*4 + r; cols: wc*64 + ni*16 + l15.
    // Restage 128-row halves (mq = wr>>1) through T[128][136] bf16.
    const int colL  = wc * 64 + (lane & 15);
    const int rbase = (wr & 1) * 64 + ((lane >> 4) << 2);
    const int mqme  = wr >> 1;

    if constexpr (MODE == 3) {
        float bvals[4];
#pragma unroll
        for (int ni = 0; ni < 4; ++ni) bvals[ni] = biasQ[n0 + colL + ni * 16];
        ushort* T = lds;                 // [128][136]
        ushort* o = (ushort*)out;
#pragma unroll
        for (int mq = 0; mq < 2; ++mq) {
            if (mqme == mq) {
#pragma unroll
                for (int mi = 0; mi < 4; ++mi)
#pragma unroll
                for (int ni = 0; ni < 4; ++ni) {
                    const int t0 = rbase + mi * 16;
#pragma unroll
                    for (int r = 0; r < 4; ++r)
                        T[(t0 + r) * 136 + colL + ni * 16] =
                            f2b(gelu_f(acc[mi][ni][r] + bvals[ni]));
                }
            }
            __syncthreads();
#pragma unroll
            for (int it = 0; it < 4; ++it) {
                const int idx = it * 512 + tid;
                const int row = idx >> 4, ch = idx & 15;
                const uint4 vv = *(const uint4*)&T[row * 136 + ch * 8];
                *(uint4*)&o[(size_t)(m0 + mq * 128 + row) * N + n0 + ch * 8] = vv;
            }
            __syncthreads();
        }
    }

    if constexpr (MODE == 1) {
        const int mat   = n0 >> 10;      // 0=Q, 1=K, 2=V (block-uniform)
        const int bb    = m0 >> 10;
        const int tbase = m0 & 1023;
        if (mat < 2) {
            // Q/K: token-major [8192][1024], plain row store (like MODE 3)
            const float* bp = (mat == 0) ? biasQ : biasK;
            ushort* dst = (mat == 0) ? (ushort*)out : (ushort*)out2;
            const int cb = n0 & 1023;
            float bvals[4];
#pragma unroll
            for (int ni = 0; ni < 4; ++ni) bvals[ni] = bp[cb + colL + ni * 16];
            ushort* T = lds;             // [128][136]
#pragma unroll
            for (int mq = 0; mq < 2; ++mq) {
                if (mqme == mq) {
#pragma unroll
                    for (int mi = 0; mi < 4; ++mi)
#pragma unroll
                    for (int ni = 0; ni < 4; ++ni) {
                        const int t0 = rbase + mi * 16;
#pragma unroll
                        for (int r = 0; r < 4; ++r)
                            T[(t0 + r) * 136 + colL + ni * 16] =
                                f2b(acc[mi][ni][r] + bvals[ni]);
                    }
                }
                __syncthreads();
#pragma unroll
                for (int it = 0; it < 4; ++it) {
                    const int idx = it * 512 + tid;
                    const int row = idx >> 4, ch = idx & 15;
                    const uint4 vv = *(const uint4*)&T[row * 136 + ch * 8];
                    *(uint4*)&dst[(size_t)(m0 + mq * 128 + row) * 1024 + cb + ch * 8] = vv;
                }
                __syncthreads();
            }
        } else {
            // V: transpose 256(t) x 128(dim) -> Vt [b,h][d][t], per 128-t half
            const int vb = n0 - 2048;
            ushort* T = lds;             // [128 dim][136 t]
            ushort* Vt = (ushort*)out3;
            float bvals[4];
#pragma unroll
            for (int ni = 0; ni < 4; ++ni) bvals[ni] = biasV[vb + colL + ni * 16];
#pragma unroll
            for (int mq = 0; mq < 2; ++mq) {
                if (mqme == mq) {
#pragma unroll
                    for (int ni = 0; ni < 4; ++ni)
#pragma unroll
                    for (int mi = 0; mi < 4; ++mi) {
                        const int t0 = rbase + mi * 16;
#pragma unroll
                        for (int r = 0; r < 4; ++r)
                            T[(colL + ni * 16) * 136 + t0 + r] =
                                f2b(acc[mi][ni][r] + bvals[ni]);
                    }
                }
                __syncthreads();
#pragma unroll
                for (int it = 0; it < 4; ++it) {
                    const int idx = it * 512 + tid;
                    const int dim = idx >> 4, ch = idx & 15;
                    const uint4 vv = *(const uint4*)&T[dim * 136 + ch * 8];
                    const int d  = vb + dim;
                    const int hh = d >> 6, dl = d & 63;
                    *(uint4*)&Vt[((size_t)(bb * 16 + hh) * 64 + dl) * 1024
                                 + tbase + mq * 128 + ch * 8] = vv;
                }
                __syncthreads();
            }
        }
    }
}

// ---------------------------------------------------------------------------
// gemm97 (MODE 2 only): 128x128 tile, 256 thr / 4 waves, 36KB LDS, m97 loop.
// fp32 out = acc + bias + resid (coalesced via LDS restage). Wo / FFN2.
// ---------------------------------------------------------------------------
__global__ __launch_bounds__(256, 4)
void gemm97r(const ushort* __restrict__ A, const ushort* __restrict__ Bt,
             const float* __restrict__ bias, float* __restrict__ out,
             const float* __restrict__ resid, int N, int K) {
    __shared__ __align__(128) ushort lds[18432];   // 36 KB

    const int tid  = threadIdx.x;
    const int lane = tid & 63;
    const int w    = tid >> 6;       // 0..3
    const int wr   = w >> 1;         // 0..1 (M half)
    const int wc   = w & 1;          // 0..1 (N half)

    int bx = blockIdx.x, by = blockIdx.y;
    {
        const int nwg = gridDim.x * gridDim.y;
        if ((nwg & 7) == 0) {
            const int flat = by * gridDim.x + bx;
            const int cpx  = nwg >> 3;
            const int wg   = (flat & 7) * cpx + (flat >> 3);
            bx = wg % gridDim.x;
            by = wg / gridDim.x;
        }
    }
    const int m0 = by * 128;
    const int n0 = bx * 128;

    floatx4 acc[4][4] = {};

    const int lr3 = lane >> 3;
    const int sc  = (lane & 7) ^ lr3;
    const ushort* pA = A  + (size_t)(m0 + w * 32 + lr3) * K + sc * 8;
    const ushort* pB = Bt + (size_t)(n0 + w * 32 + lr3) * K + sc * 8;
    ushort* sAd = lds + w * 2048;
    ushort* sBd = lds + 8192 + w * 2048;
    const size_t k8 = (size_t)8 * K, k16 = (size_t)16 * K, k24 = (size_t)24 * K;

    const int c0f = (lane >> 4) ^ (lane & 7);
    const int aIdx = (wr * 64 + (lane & 15)) * 64 + c0f * 8;
    const int bIdx = (wc * 64 + (lane & 15)) * 64 + c0f * 8;
    const ushort* ar0 = lds + aIdx;
    const ushort* ar1 = lds + (aIdx ^ 32);
    const ushort* br0 = lds + 8192 + bIdx;
    const ushort* br1 = lds + 8192 + (bIdx ^ 32);

    for (int k0 = 0; k0 < K; k0 += 64) {
        __syncthreads();
        gl_lds16(pA + k0,       sAd);
        gl_lds16(pA + k8  + k0, sAd + 512);
        gl_lds16(pA + k16 + k0, sAd + 1024);
        gl_lds16(pA + k24 + k0, sAd + 1536);
        gl_lds16(pB + k0,       sBd);
        gl_lds16(pB + k8  + k0, sBd + 512);
        gl_lds16(pB + k16 + k0, sBd + 1024);
        gl_lds16(pB + k24 + k0, sBd + 1536);
        asm volatile("s_waitcnt vmcnt(0)" ::: "memory");
        __syncthreads();

        shortx8 af[4][2], bf[4][2];
#pragma unroll
        for (int mi = 0; mi < 4; ++mi) {
            af[mi][0] = *(const shortx8*)&ar0[mi * 1024];
            af[mi][1] = *(const shortx8*)&ar1[mi * 1024];
        }
#pragma unroll
        for (int ni = 0; ni < 4; ++ni) {
            bf[ni][0] = *(const shortx8*)&br0[ni * 1024];
            bf[ni][1] = *(const shortx8*)&br1[ni * 1024];
        }
#pragma unroll
        for (int mi = 0; mi < 4; ++mi)
#pragma unroll
            for (int ni = 0; ni < 4; ++ni) {
                acc[mi][ni] = __builtin_amdgcn_mfma_f32_16x16x32_bf16(
                    af[mi][0], bf[ni][0], acc[mi][ni], 0, 0, 0);
                acc[mi][ni] = __builtin_amdgcn_mfma_f32_16x16x32_bf16(
                    af[mi][1], bf[ni][1], acc[mi][ni], 0, 0, 0);
            }
    }
    __syncthreads();

    const int colL  = wc * 64 + (lane & 15);
    const int rbase = wr * 64 + ((lane >> 4) << 2);
    float bvals[4];
#pragma unroll
    for (int ni = 0; ni < 4; ++ni) bvals[ni] = bias[n0 + colL + ni * 16];
    float* T = (float*)lds;              // [64][132]
    float* o = (float*)out;
#pragma unroll
    for (int half = 0; half < 2; ++half) {
        if (wr == half) {
#pragma unroll
            for (int mi = 0; mi < 4; ++mi)
#pragma unroll
            for (int ni = 0; ni < 4; ++ni) {
                const int t0 = mi * 16 + ((lane >> 4) << 2);
#pragma unroll
                for (int r = 0; r < 4; ++r)
                    T[(t0 + r) * 132 + colL + ni * 16] =
                        acc[mi][ni][r] + bvals[ni];
            }
        }
        __syncthreads();
#pragma unroll
        for (int it = 0; it < 8; ++it) {
            const int idx = it * 256 + tid;
            const int row = idx >> 5, ch = idx & 31;
            float4 tv = *(const float4*)&T[row * 132 + ch * 4];
            const size_t go = (size_t)(m0 + half * 64 + row) * N + n0 + ch * 4;
            const float4 rv = *(const float4*)&resid[go];
            tv.x += rv.x; tv.y += rv.y; tv.z += rv.z; tv.w += rv.w;
            *(float4*)&o[go] = tv;
        }
        __syncthreads();
    }
}

// ---------------------------------------------------------------------------
// Flash-style causal attention. Q,K token-major [8192][1024]; V^T [b,h][d][t].
// ---------------------------------------------------------------------------
__global__ __launch_bounds__(256)
void attn_kernel(const ushort* __restrict__ Q, const ushort* __restrict__ Kk,
                 const ushort* __restrict__ Vt, ushort* __restrict__ ctx) {
    __shared__ ushort sK[64 * 64];
    __shared__ ushort sV[64 * 64];     // V^T tile: [d][64 kv-cols]
    __shared__ ushort sP[4][16 * 72];

    const int tid  = threadIdx.x;
    const int lane = tid & 63;
    const int wave = tid >> 6;
    const int quad = lane >> 4;
    const int l15  = lane & 15;

    const int qb = 15 - (blockIdx.x >> 7);   // descending workload
    const int bh = blockIdx.x & 127;
    const size_t vbase = (size_t)bh << 16;   // bh*64*1024 (V^T layout)
    const int bb = bh >> 4, h = bh & 15;

    const int lrow = lane >> 3;
    const int scb  = (lane & 7) ^ lrow;
    // K token-major: row = bb*1024 + kv_token, col = h*64 + (0..63)
    const ushort* Kg = Kk + ((size_t)bb * 1024 + wave * 8 + lrow) * 1024 + h * 64 + scb * 8;
    const ushort* Vg = Vt + vbase + (size_t)(wave * 8 + lrow) * 1024 + scb * 8;

    const int qrow = bb * 1024 + qb * 64 + wave * 16 + l15;
    const shortx8 qf0 = *(const shortx8*)&Q[(size_t)qrow * 1024 + h * 64 + quad * 8];
    const shortx8 qf1 = *(const shortx8*)&Q[(size_t)qrow * 1024 + h * 64 + 32 + quad * 8];

    const float SC = 0.125f * 1.44269504f;   // exp2-domain scaling

    float mstate[4], lstate[4];
    floatx4 oacc[4] = {};
#pragma unroll
    for (int r = 0; r < 4; ++r) { mstate[r] = -__builtin_inff(); lstate[r] = 0.0f; }

    for (int kt = 0; kt <= qb; ++kt) {
        __syncthreads();
#pragma unroll
        for (int p = 0; p < 2; ++p) {
            gl_lds16(Kg + (size_t)kt * 65536 + (size_t)p * 32768,
                     sK + (p * 32 + wave * 8) * 64);
            gl_lds16(Vg + (size_t)kt * 64 + (size_t)p * 32 * 1024,
                     sV + (p * 32 + wave * 8) * 64);
        }
        __syncthreads();

        floatx4 s[4];
#pragma unroll
        for (int nt = 0; nt < 4; ++nt) {
            const int r = nt * 16 + l15;
            const int c0 = quad ^ (r & 7);
            const int c1 = (4 + quad) ^ (r & 7);
            const shortx8 kf0 = *(const shortx8*)&sK[r * 64 + c0 * 8];
            const shortx8 kf1 = *(const shortx8*)&sK[r * 64 + c1 * 8];
            floatx4 z = {};
            z = __builtin_amdgcn_mfma_f32_16x16x32_bf16(qf0, kf0, z, 0, 0, 0);
            z = __builtin_amdgcn_mfma_f32_16x16x32_bf16(qf1, kf1, z, 0, 0, 0);
            s[nt] = z;
        }
#pragma unroll
        for (int nt = 0; nt < 4; ++nt)
#pragma unroll
            for (int r = 0; r < 4; ++r) {
                float sv = s[nt][r] * SC;
                if (kt == qb) {
                    const int col = nt * 16 + l15;
                    const int row = wave * 16 + quad * 4 + r;
                    if (col > row) sv = -__builtin_inff();
                }
                s[nt][r] = sv;
            }
        float mnew[4], alpha[4];
#pragma unroll
        for (int r = 0; r < 4; ++r) {
            float mt = fmaxf(fmaxf(s[0][r], s[1][r]), fmaxf(s[2][r], s[3][r]));
#pragma unroll
            for (int o = 8; o >= 1; o >>= 1) mt = fmaxf(mt, __shfl_xor(mt, o, 64));
            mnew[r]  = fmaxf(mstate[r], mt);
            alpha[r] = exp2f(mstate[r] - mnew[r]);
            mstate[r] = mnew[r];
        }
#pragma unroll
        for (int r = 0; r < 4; ++r) {
            float rs = 0.0f;
#pragma unroll
            for (int nt = 0; nt < 4; ++nt) {
                const float p = exp2f(s[nt][r] - mnew[r]);
                s[nt][r] = p;
                rs += p;
            }
#pragma unroll
            for (int o = 8; o >= 1; o >>= 1) rs += __shfl_xor(rs, o, 64);
            lstate[r] = alpha[r] * lstate[r] + rs;
#pragma unroll
            for (int dt = 0; dt < 4; ++dt) oacc[dt][r] *= alpha[r];
        }
#pragma unroll
        for (int nt = 0; nt < 4; ++nt)
#pragma unroll
            for (int r = 0; r < 4; ++r)
                sP[wave][(quad * 4 + r) * 72 + nt * 16 + l15] = f2b(s[nt][r]);
        __asm__ volatile("s_waitcnt lgkmcnt(0)" ::: "memory");
        const shortx8 pf0 = *(const shortx8*)&sP[wave][l15 * 72 + quad * 8];
        const shortx8 pf1 = *(const shortx8*)&sP[wave][l15 * 72 + 32 + quad * 8];
#pragma unroll
        for (int dt = 0; dt < 4; ++dt) {
            const int r = dt * 16 + l15;
            const int c0 = quad ^ (r & 7);
            const int c1 = (4 + quad) ^ (r & 7);
            const shortx8 v0 = *(const shortx8*)&sV[r * 64 + c0 * 8];
            const shortx8 v1 = *(const shortx8*)&sV[r * 64 + c1 * 8];
            oacc[dt] = __builtin_amdgcn_mfma_f32_16x16x32_bf16(pf0, v0, oacc[dt], 0, 0, 0);
            oacc[dt] = __builtin_amdgcn_mfma_f32_16x16x32_bf16(pf1, v1, oacc[dt], 0, 0, 0);
        }
    }
#pragma unroll
    for (int dt = 0; dt < 4; ++dt)
#pragma unroll
        for (int r = 0; r < 4; ++r) {
            const int t = qb * 64 + wave * 16 + quad * 4 + r;
            const int dim = dt * 16 + l15;
            const float v = oacc[dt][r] / lstate[r];
            ctx[(size_t)(bb * 1024 + t) * 1024 + h * 64 + dim] = f2b(v);
        }
}

// ---------------------------------------------------------------------------
// Launch
// ---------------------------------------------------------------------------
extern "C" void kernel_launch(void* const* d_in, const int* in_sizes, int n_in,
                              void* d_out, int out_size, void* d_ws, size_t ws_size,
                              hipStream_t stream) {
    const float* x    = (const float*)d_in[0];
    const float* ln1w = (const float*)d_in[2];
    const float* ln1b = (const float*)d_in[3];
    const float* ln2w = (const float*)d_in[4];
    const float* ln2b = (const float*)d_in[5];
    const float* wq   = (const float*)d_in[6];
    const float* bq   = (const float*)d_in[7];
    const float* wk   = (const float*)d_in[8];
    const float* bk   = (const float*)d_in[9];
    const float* wv   = (const float*)d_in[10];
    const float* bv   = (const float*)d_in[11];
    const float* wo   = (const float*)d_in[12];
    const float* bo   = (const float*)d_in[13];
    const float* w1   = (const float*)d_in[14];
    const float* b1   = (const float*)d_in[15];
    const float* w2   = (const float*)d_in[16];
    const float* b2   = (const float*)d_in[17];

    char* ws = (char*)d_ws;
    const size_t MB = 1024 * 1024;
    ushort* WQKVT = (ushort*)(ws + 0 * MB);     // [3072][1024] bf16 (wq|wk|wv ^T)
    ushort* WOT   = (ushort*)(ws + 6 * MB);     // [1024][1024]
    ushort* W1T   = (ushort*)(ws + 8 * MB);     // [4096][1024]
    ushort* W2T   = (ushort*)(ws + 16 * MB);    // [1024][4096]
    ushort* H1    = (ushort*)(ws + 24 * MB);    // [8192][1024]; H2 overlays later
    ushort* H2    = H1;
    ushort* Qb    = (ushort*)(ws + 40 * MB);    // [8192][1024] token-major
    ushort* Kb    = (ushort*)(ws + 56 * MB);    // [8192][1024] token-major
    ushort* Vbt   = (ushort*)(ws + 72 * MB);    // [128][64][1024]
    ushort* FF1   = (ushort*)(ws + 40 * MB);    // [8192][4096] overlays Q,K,V (dead)
    ushort* CTX   = (ushort*)(ws + 104 * MB);   // [8192][1024]

    float* xout = (float*)d_out;                // x2 lives here, then final out

    const dim3 tb(32, 8);
    transp4_kernel<<<dim3(32, 32, 4), tb, 0, stream>>>(
        wq, wk, wv, wo,
        WQKVT, WQKVT + 1024 * 1024, WQKVT + 2048 * 1024, WOT);
    transp_kernel<<<dim3(128, 32), tb, 0, stream>>>(w1, W1T, 1024, 4096);
    transp_kernel<<<dim3(32, 128), tb, 0, stream>>>(w2, W2T, 4096, 1024);

    ln_kernel<<<8192, 256, 0, stream>>>(x, ln1w, ln1b, H1);

    gemmW<1><<<dim3(24, 32), 512, 0, stream>>>(H1, WQKVT, bq, bk, bv,
                                               Qb, Kb, Vbt, 3072, 1024);

    attn_kernel<<<2048, 256, 0, stream>>>(Qb, Kb, Vbt, CTX);

    gemm97r<<<dim3(8, 64), 256, 0, stream>>>(CTX, WOT, bo, xout, x, 1024, 1024);

    ln_kernel<<<8192, 256, 0, stream>>>(xout, ln2w, ln2b, H2);

    gemmW<3><<<dim3(32, 32), 512, 0, stream>>>(H2, W1T, b1, nullptr, nullptr,
                                               FF1, nullptr, nullptr, 4096, 1024);

    gemm97r<<<dim3(8, 64), 256, 0, stream>>>(FF1, W2T, b2, xout, xout, 1024, 4096);

    (void)in_sizes; (void)n_in; (void)out_size; (void)ws_size;
}